// Round 15
// baseline (122.999 us; speedup 1.0000x reference)
//
#include <hip/hip_runtime.h>
#include <hip/hip_bf16.h>

#define PIX 256
#define CROP 14
#define HW2 196
#define BB 128
#define CC 512
#define NC 384
#define NO 768
#define CAP 128
#define EQ 6272       // entries per (t,q) = 128*49

typedef __bf16 bf16x8 __attribute__((ext_vector_type(8)));
typedef float  f32x4  __attribute__((ext_vector_type(4)));
typedef unsigned int u32;

#define GLOAD_LDS16(src, dst) \
    __builtin_amdgcn_global_load_lds((const __attribute__((address_space(1))) void*)(src), \
                                     (__attribute__((address_space(3))) void*)(dst), 16, 0, 0)

__global__ void wconv_kernel(const float* __restrict__ W, __bf16* __restrict__ Wb) {
    int tid = blockIdx.x * 256 + threadIdx.x;
    Wb[tid] = (__bf16)W[tid];
}

// entry word: (c3loc<<25) | (hw<<17) | (p<<9) | ch
// bucket index: t*2048 + (hw/49)*512 + ch   (6144 buckets)
__global__ void fill_kernel(const int* __restrict__ idx, const int* __restrict__ offh,
                            const int* __restrict__ offw, int* __restrict__ cnt,
                            u32* __restrict__ bucket) {
    int tid = blockIdx.x * 256 + threadIdx.x;   // < 75264
    int c3 = tid / HW2;
    int hw = tid - c3 * HW2;
    int i = hw / CROP, j = hw - i * CROP;
    int p = (offh[c3] + i) * 16 + offw[c3] + j;
    int ch = idx[c3 * PIX + p];
    int q = hw / 49;
    int bkt = (c3 >> 7) * 2048 + q * 512 + ch;
    int pos = atomicAdd(&cnt[bkt], 1);
    if (pos < CAP)
        bucket[bkt * CAP + pos] =
            ((u32)(c3 & 127) << 25) | ((u32)hw << 17) | ((u32)p << 9) | (u32)ch;
}

// exclusive prefix over 6144 clamped counts (single block, 24 per thread)
__global__ __launch_bounds__(256) void scan_kernel(const int* __restrict__ cnt,
                                                   int* __restrict__ pref) {
    __shared__ int part[256];
    int tid = threadIdx.x;
    int loc[24];
    int s = 0;
#pragma unroll
    for (int i = 0; i < 24; ++i) {
        int v = cnt[tid * 24 + i]; if (v > CAP) v = CAP;
        loc[i] = s; s += v;
    }
    part[tid] = s;
    __syncthreads();
    if (tid < 64) {
        int l4[4]; int s4 = 0;
#pragma unroll
        for (int i = 0; i < 4; ++i) { l4[i] = s4; s4 += part[tid * 4 + i]; }
        int v = s4;
#pragma unroll
        for (int d = 1; d < 64; d <<= 1) { int u = __shfl_up(v, d); if (tid >= d) v += u; }
        int excl = v - s4;
#pragma unroll
        for (int i = 0; i < 4; ++i) part[tid * 4 + i] = excl + l4[i];
    }
    __syncthreads();
    int off = part[tid];
#pragma unroll
    for (int i = 0; i < 24; ++i) pref[tid * 24 + i] = off + loc[i];
}

// dense entry list, ordered (t, q, ch); base of (t,q) = (t*4+q)*6272 exactly
__global__ __launch_bounds__(128) void compact_kernel(const int* __restrict__ cnt,
                                                      const int* __restrict__ pref,
                                                      const u32* __restrict__ bucket,
                                                      u32* __restrict__ ent) {
    int bkt = blockIdx.x;
    int E = cnt[bkt]; if (E > CAP) E = CAP;
    int tid = threadIdx.x;
    if (tid < E) ent[pref[bkt] + tid] = bucket[bkt * CAP + tid];
}

// scatter v11: R13 structure + 8-deep inline-asm gather batches.
// 8 global_load_dword issued back-to-back into 8 named outputs (compiler-proof
// MLP; <=8 outputs keeps VGPR ~50 -> no spill, the R10/R11 failure mode),
// then one vmcnt(0) + sched_barrier(0) (rule #18) before the consumes.
__global__ __launch_bounds__(256) void scatter_kernel(
        const float* __restrict__ x1, const float* __restrict__ x3,
        const float* __restrict__ x5, const u32* __restrict__ ent,
        __bf16* __restrict__ feats) {
    __shared__ __bf16 fl[49 * 128];          // 12544 B
    int d = blockIdx.x;                      // 1536 = 8 XCD * 192
    int wg = (d & 7) * 192 + (d >> 3);
    int b = wg / 12, tq = wg - b * 12;
    int t = tq >> 2, q = tq & 3;
    const float* x = (t == 0) ? x1 : (t == 1) ? x3 : x5;
    const float* xb = x + (size_t)b * CC * PIX;
    const u32* el = ent + tq * EQ;
    int tid = threadIdx.x;

    // 3 batches of 8 strided entries: covers 6144 of 6272
    for (int base = 0; base < 6144; base += 2048) {
        u32 wd[8];
#pragma unroll
        for (int k = 0; k < 8; ++k) wd[k] = el[base + k * 256 + tid];
        u32 fbits[8];
#pragma unroll
        for (int k = 0; k < 8; ++k) {
            const float* ap = xb + (size_t)((wd[k] & 511) * PIX + ((wd[k] >> 9) & 255));
            asm volatile("global_load_dword %0, %1, off" : "=v"(fbits[k]) : "v"(ap));
        }
        asm volatile("s_waitcnt vmcnt(0)" ::: "memory");
        __builtin_amdgcn_sched_barrier(0);
#pragma unroll
        for (int k = 0; k < 8; ++k) {
            int hw = (wd[k] >> 17) & 255;
            int c3 = (int)(wd[k] >> 25);
            fl[(hw - q * 49) * 128 + c3] = (__bf16)__builtin_bit_cast(float, fbits[k]);
        }
    }
    // tail: entries 6144..6271
    if (tid < 128) {
        u32 wd = el[6144 + tid];
        float f = xb[(wd & 511) * PIX + ((wd >> 9) & 255)];
        fl[(((wd >> 17) & 255) - q * 49) * 128 + (wd >> 25)] = (__bf16)f;
    }
    __syncthreads();

    const size_t obase = ((size_t)b * HW2 + q * 49) * NC + (size_t)t * 128;
    for (int i2 = tid; i2 < 49 * 16; i2 += 256) {
        int hwl = i2 >> 4, ck = (i2 & 15) * 8;
        *(bf16x8*)(feats + obase + (size_t)hwl * NC + ck) = *(const bf16x8*)&fl[hwl * 128 + ck];
    }
}

// GEMM: m97 structure, 128x128 tile, BK=64, XOR-swizzled LDS via pre-swizzled
// source. Epilogue uses NON-TEMPORAL stores: out (77MB) is never re-read in
// this iteration; bypassing LLC keeps x1/x3/x5 (192MB) resident for scatter.
__global__ __launch_bounds__(256) void gemm_kernel(const __bf16* __restrict__ feats,
                                                   const __bf16* __restrict__ Wb,
                                                   float* __restrict__ out) {
    __shared__ __bf16 ldsbuf[16384];           // A [128][64] @0, B [128][64] @8192
    __bf16* Abuf = ldsbuf;
    __bf16* Bbuf = ldsbuf + 8192;

    const int d = blockIdx.x;                  // 1176 blocks, 147 per XCD
    const int wg = (d & 7) * 147 + (d >> 3);
    const int o_base = (wg % 6) * 128;
    const int m_base = (wg / 6) * 128;

    const int tid = threadIdx.x;
    const int wave = tid >> 6, lane = tid & 63;
    const int wo = wave >> 1, wm = wave & 1;
    const int l15 = lane & 15, g = lane >> 4;
    const int xr = l15 & 7;

    f32x4 acc[4][4] = {};

    for (int kt = 0; kt < 6; ++kt) {
        const int k0g = kt * 64;
#pragma unroll
        for (int it = 0; it < 4; ++it) {
            int ck = tid + it * 256;
            int row = ck >> 3, cc = ck & 7;
            int koff = k0g + ((cc ^ (row & 7)) << 3);
            GLOAD_LDS16(Wb    + (size_t)(o_base + row) * NC + koff, Abuf + ck * 8);
            GLOAD_LDS16(feats + (size_t)(m_base + row) * NC + koff, Bbuf + ck * 8);
        }
        __syncthreads();
#pragma unroll
        for (int k0 = 0; k0 < 64; k0 += 32) {
            const int cb = (k0 >> 3) + g;
            bf16x8 a[4], b[4];
#pragma unroll
            for (int s = 0; s < 4; ++s) {
                int arow = wo * 64 + s * 16 + l15;
                a[s] = *(const bf16x8*)&Abuf[arow * 64 + ((cb ^ xr) << 3)];
                int brow = wm * 64 + s * 16 + l15;
                b[s] = *(const bf16x8*)&Bbuf[brow * 64 + ((cb ^ xr) << 3)];
            }
#pragma unroll
            for (int os = 0; os < 4; ++os)
#pragma unroll
                for (int ms = 0; ms < 4; ++ms)
                    acc[os][ms] = __builtin_amdgcn_mfma_f32_16x16x32_bf16(a[os], b[ms], acc[os][ms], 0, 0, 0);
        }
        __syncthreads();
    }

#pragma unroll
    for (int os = 0; os < 4; ++os)
#pragma unroll
        for (int ms = 0; ms < 4; ++ms) {
            int m = m_base + wm * 64 + ms * 16 + l15;
            int bb = m / HW2;
            int hw = m - bb * HW2;
            int o = o_base + wo * 64 + os * 16 + g * 4;
            float* dst = out + ((size_t)bb * NO + o) * HW2 + hw;
            f32x4 v = acc[os][ms];
            __builtin_nontemporal_store(v[0], dst + 0 * HW2);
            __builtin_nontemporal_store(v[1], dst + 1 * HW2);
            __builtin_nontemporal_store(v[2], dst + 2 * HW2);
            __builtin_nontemporal_store(v[3], dst + 3 * HW2);
        }
}

extern "C" void kernel_launch(void* const* d_in, const int* in_sizes, int n_in,
                              void* d_out, int out_size, void* d_ws, size_t ws_size,
                              hipStream_t stream) {
    const float* x1   = (const float*)d_in[0];
    const float* x3   = (const float*)d_in[1];
    const float* x5   = (const float*)d_in[2];
    const float* W    = (const float*)d_in[3];
    const int*   idx  = (const int*)d_in[4];
    const int*   offh = (const int*)d_in[5];
    const int*   offw = (const int*)d_in[6];
    float* out = (float*)d_out;

    char* ws = (char*)d_ws;
    __bf16* feats  = (__bf16*)(ws);              // 19,267,584 B
    __bf16* Wb     = (__bf16*)(ws + 19267584);   // 589,824 B
    int*    cnt    = (int*)   (ws + 19857408);   // 24,576 B
    int*    pref   = (int*)   (ws + 19881984);   // 24,576 B
    u32*    bucket = (u32*)   (ws + 19906560);   // 3,145,728 B
    u32*    ent    = (u32*)   (ws + 23052288);   // 301,056 B

    wconv_kernel<<<(NO * NC) / 256, 256, 0, stream>>>(W, Wb);
    hipMemsetAsync(cnt, 0, 6144 * sizeof(int), stream);
    fill_kernel<<<(NC * HW2) / 256, 256, 0, stream>>>(idx, offh, offw, cnt, bucket);
    scan_kernel<<<1, 256, 0, stream>>>(cnt, pref);
    compact_kernel<<<6144, 128, 0, stream>>>(cnt, pref, bucket, ent);
    scatter_kernel<<<1536, 256, 0, stream>>>(x1, x3, x5, ent, feats);
    gemm_kernel<<<1176, 256, 0, stream>>>(feats, Wb, out);
}

// Round 16
// 94.953 us; speedup vs baseline: 1.2954x; 1.2954x over previous
//
#include <hip/hip_runtime.h>
#include <hip/hip_bf16.h>

#define PIX 256
#define CROP 14
#define HW2 196
#define BB 128
#define CC 512
#define NC 384
#define NO 768
#define CAP 128
#define EQ 6272       // entries per (t,q) = 128*49

typedef __bf16 bf16x8 __attribute__((ext_vector_type(8)));
typedef float  f32x4  __attribute__((ext_vector_type(4)));
typedef unsigned int u32;

#define GLOAD_LDS16(src, dst) \
    __builtin_amdgcn_global_load_lds((const __attribute__((address_space(1))) void*)(src), \
                                     (__attribute__((address_space(3))) void*)(dst), 16, 0, 0)

// wconv + cnt-zeroing fused (saves one dispatch; wconv completes before fill
// on the in-order stream, so the zeroing is ordered before fill's atomics).
__global__ void wconv_kernel(const float* __restrict__ W, __bf16* __restrict__ Wb,
                             int* __restrict__ cnt) {
    int tid = blockIdx.x * 256 + threadIdx.x;
    Wb[tid] = (__bf16)W[tid];
    if (tid < 6144) cnt[tid] = 0;
}

// entry word: (c3loc<<25) | (hw<<17) | (p<<9) | ch
// bucket index: t*2048 + (hw/49)*512 + ch   (6144 buckets)
__global__ void fill_kernel(const int* __restrict__ idx, const int* __restrict__ offh,
                            const int* __restrict__ offw, int* __restrict__ cnt,
                            u32* __restrict__ bucket) {
    int tid = blockIdx.x * 256 + threadIdx.x;   // < 75264
    int c3 = tid / HW2;
    int hw = tid - c3 * HW2;
    int i = hw / CROP, j = hw - i * CROP;
    int p = (offh[c3] + i) * 16 + offw[c3] + j;
    int ch = idx[c3 * PIX + p];
    int q = hw / 49;
    int bkt = (c3 >> 7) * 2048 + q * 512 + ch;
    int pos = atomicAdd(&cnt[bkt], 1);
    if (pos < CAP)
        bucket[bkt * CAP + pos] =
            ((u32)(c3 & 127) << 25) | ((u32)hw << 17) | ((u32)p << 9) | (u32)ch;
}

// exclusive prefix over 6144 clamped counts (single block, 24 per thread)
__global__ __launch_bounds__(256) void scan_kernel(const int* __restrict__ cnt,
                                                   int* __restrict__ pref) {
    __shared__ int part[256];
    int tid = threadIdx.x;
    int loc[24];
    int s = 0;
#pragma unroll
    for (int i = 0; i < 24; ++i) {
        int v = cnt[tid * 24 + i]; if (v > CAP) v = CAP;
        loc[i] = s; s += v;
    }
    part[tid] = s;
    __syncthreads();
    if (tid < 64) {
        int l4[4]; int s4 = 0;
#pragma unroll
        for (int i = 0; i < 4; ++i) { l4[i] = s4; s4 += part[tid * 4 + i]; }
        int v = s4;
#pragma unroll
        for (int d = 1; d < 64; d <<= 1) { int u = __shfl_up(v, d); if (tid >= d) v += u; }
        int excl = v - s4;
#pragma unroll
        for (int i = 0; i < 4; ++i) part[tid * 4 + i] = excl + l4[i];
    }
    __syncthreads();
    int off = part[tid];
#pragma unroll
    for (int i = 0; i < 24; ++i) pref[tid * 24 + i] = off + loc[i];
}

// dense entry list, ordered (t, q, ch); base of (t,q) = (t*4+q)*6272 exactly
__global__ __launch_bounds__(128) void compact_kernel(const int* __restrict__ cnt,
                                                      const int* __restrict__ pref,
                                                      const u32* __restrict__ bucket,
                                                      u32* __restrict__ ent) {
    int bkt = blockIdx.x;
    int E = cnt[bkt]; if (E > CAP) E = CAP;
    int tid = threadIdx.x;
    if (tid < E) ent[pref[bkt] + tid] = bucket[bkt * CAP + tid];
}

// scatter v10 (R13 best): block = (b, t, hw-quarter q): 1536 blocks,
// LDS 12.5KB, ~24 waves/CU. Sequential ch-sorted sweep of x[b], LDS tile
// fl[49][128] (each cell exactly once), coalesced writeout to feats.
// Measured service-rate bound: ~80us at ~1.4TB/s (MLP/width/occupancy/
// contiguity all ablated null, R4-R14).
__global__ __launch_bounds__(256) void scatter_kernel(
        const float* __restrict__ x1, const float* __restrict__ x3,
        const float* __restrict__ x5, const u32* __restrict__ ent,
        __bf16* __restrict__ feats) {
    __shared__ __bf16 fl[49 * 128];          // 12544 B
    int d = blockIdx.x;                      // 1536 = 8 XCD * 192
    int wg = (d & 7) * 192 + (d >> 3);
    int b = wg / 12, tq = wg - b * 12;
    int t = tq >> 2, q = tq & 3;
    const float* x = (t == 0) ? x1 : (t == 1) ? x3 : x5;
    const float* xb = x + (size_t)b * CC * PIX;
    const u32* el = ent + tq * EQ;
    int tid = threadIdx.x;

    for (int g = tid; g < EQ; g += 256) {
        u32 wd = el[g];                      // coalesced, ascending ch
        int ch = wd & 511;
        int p  = (wd >> 9) & 255;
        int hw = (wd >> 17) & 255;
        int c3 = wd >> 25;
        float f = xb[ch * PIX + p];
        fl[(hw - q * 49) * 128 + c3] = (__bf16)f;
    }
    __syncthreads();

    const size_t obase = ((size_t)b * HW2 + q * 49) * NC + (size_t)t * 128;
    for (int i2 = tid; i2 < 49 * 16; i2 += 256) {
        int hwl = i2 >> 4, ck = (i2 & 15) * 8;
        *(bf16x8*)(feats + obase + (size_t)hwl * NC + ck) = *(const bf16x8*)&fl[hwl * 128 + ck];
    }
}

// GEMM: m97 structure, 128x128 tile, BK=64, XOR-swizzled LDS via pre-swizzled source.
__global__ __launch_bounds__(256) void gemm_kernel(const __bf16* __restrict__ feats,
                                                   const __bf16* __restrict__ Wb,
                                                   float* __restrict__ out) {
    __shared__ __bf16 ldsbuf[16384];           // A [128][64] @0, B [128][64] @8192
    __bf16* Abuf = ldsbuf;
    __bf16* Bbuf = ldsbuf + 8192;

    const int d = blockIdx.x;                  // 1176 blocks, 147 per XCD
    const int wg = (d & 7) * 147 + (d >> 3);
    const int o_base = (wg % 6) * 128;
    const int m_base = (wg / 6) * 128;

    const int tid = threadIdx.x;
    const int wave = tid >> 6, lane = tid & 63;
    const int wo = wave >> 1, wm = wave & 1;
    const int l15 = lane & 15, g = lane >> 4;
    const int xr = l15 & 7;

    f32x4 acc[4][4] = {};

    for (int kt = 0; kt < 6; ++kt) {
        const int k0g = kt * 64;
#pragma unroll
        for (int it = 0; it < 4; ++it) {
            int ck = tid + it * 256;
            int row = ck >> 3, cc = ck & 7;
            int koff = k0g + ((cc ^ (row & 7)) << 3);
            GLOAD_LDS16(Wb    + (size_t)(o_base + row) * NC + koff, Abuf + ck * 8);
            GLOAD_LDS16(feats + (size_t)(m_base + row) * NC + koff, Bbuf + ck * 8);
        }
        __syncthreads();
#pragma unroll
        for (int k0 = 0; k0 < 64; k0 += 32) {
            const int cb = (k0 >> 3) + g;
            bf16x8 a[4], b[4];
#pragma unroll
            for (int s = 0; s < 4; ++s) {
                int arow = wo * 64 + s * 16 + l15;
                a[s] = *(const bf16x8*)&Abuf[arow * 64 + ((cb ^ xr) << 3)];
                int brow = wm * 64 + s * 16 + l15;
                b[s] = *(const bf16x8*)&Bbuf[brow * 64 + ((cb ^ xr) << 3)];
            }
#pragma unroll
            for (int os = 0; os < 4; ++os)
#pragma unroll
                for (int ms = 0; ms < 4; ++ms)
                    acc[os][ms] = __builtin_amdgcn_mfma_f32_16x16x32_bf16(a[os], b[ms], acc[os][ms], 0, 0, 0);
        }
        __syncthreads();
    }

#pragma unroll
    for (int os = 0; os < 4; ++os)
#pragma unroll
        for (int ms = 0; ms < 4; ++ms) {
            int m = m_base + wm * 64 + ms * 16 + l15;
            int bb = m / HW2;
            int hw = m - bb * HW2;
            int o = o_base + wo * 64 + os * 16 + g * 4;
            float* dst = out + ((size_t)bb * NO + o) * HW2 + hw;
            f32x4 v = acc[os][ms];
            dst[0 * HW2] = v[0];
            dst[1 * HW2] = v[1];
            dst[2 * HW2] = v[2];
            dst[3 * HW2] = v[3];
        }
}

extern "C" void kernel_launch(void* const* d_in, const int* in_sizes, int n_in,
                              void* d_out, int out_size, void* d_ws, size_t ws_size,
                              hipStream_t stream) {
    const float* x1   = (const float*)d_in[0];
    const float* x3   = (const float*)d_in[1];
    const float* x5   = (const float*)d_in[2];
    const float* W    = (const float*)d_in[3];
    const int*   idx  = (const int*)d_in[4];
    const int*   offh = (const int*)d_in[5];
    const int*   offw = (const int*)d_in[6];
    float* out = (float*)d_out;

    char* ws = (char*)d_ws;
    __bf16* feats  = (__bf16*)(ws);              // 19,267,584 B
    __bf16* Wb     = (__bf16*)(ws + 19267584);   // 589,824 B
    int*    cnt    = (int*)   (ws + 19857408);   // 24,576 B
    int*    pref   = (int*)   (ws + 19881984);   // 24,576 B
    u32*    bucket = (u32*)   (ws + 19906560);   // 3,145,728 B
    u32*    ent    = (u32*)   (ws + 23052288);   // 301,056 B

    wconv_kernel<<<(NO * NC) / 256, 256, 0, stream>>>(W, Wb, cnt);
    fill_kernel<<<(NC * HW2) / 256, 256, 0, stream>>>(idx, offh, offw, cnt, bucket);
    scan_kernel<<<1, 256, 0, stream>>>(cnt, pref);
    compact_kernel<<<6144, 128, 0, stream>>>(cnt, pref, bucket, ent);
    scatter_kernel<<<1536, 256, 0, stream>>>(x1, x3, x5, ent, feats);
    gemm_kernel<<<1176, 256, 0, stream>>>(feats, Wb, out);
}